// Round 2
// baseline (175.702 us; speedup 1.0000x reference)
//
#include <hip/hip_runtime.h>
#include <hip/hip_bf16.h>

// Problem constants
#define F_    2
#define H_    32
#define W_    32
#define NTOK  2048          // F_*H_*W_
#define INNER 512           // HEADS*DHEAD
#define HEADS 8
#define DHEAD 64

// 64x64 tile SGEMM, fp32. M,N multiples of 64; K multiple of 16.
// C = A(MxK) * B(KxN) [+ bias]
template <bool BIAS>
__global__ __launch_bounds__(256) void gemm_tile(const float* __restrict__ A,
                                                 const float* __restrict__ B,
                                                 const float* __restrict__ bias,
                                                 float* __restrict__ C,
                                                 int M, int N, int K) {
  __shared__ __align__(16) float As[16][68];  // transposed A tile: As[k][m]
  __shared__ __align__(16) float Bs[16][64];
  const int tx = threadIdx.x & 15;
  const int ty = threadIdx.x >> 4;
  const int m0 = blockIdx.y * 64;
  const int n0 = blockIdx.x * 64;

  // A staging: thread loads 4 consecutive k's of one row (16B aligned)
  const int arow = threadIdx.x >> 2;        // 0..63
  const int acol = (threadIdx.x & 3) * 4;   // 0,4,8,12
  // B staging: thread loads 4 consecutive columns of one k-row (16B aligned)
  const int brow = threadIdx.x >> 4;        // 0..15
  const int bcol = (threadIdx.x & 15) * 4;  // 0..60

  const float* Ap = A + (size_t)(m0 + arow) * K + acol;
  const float* Bp = B + (size_t)brow * N + n0 + bcol;

  float acc[4][4] = {};

  for (int k0 = 0; k0 < K; k0 += 16) {
    {
      float4 at = *(const float4*)(Ap + k0);
      As[acol + 0][arow] = at.x;
      As[acol + 1][arow] = at.y;
      As[acol + 2][arow] = at.z;
      As[acol + 3][arow] = at.w;
      *(float4*)&Bs[brow][bcol] = *(const float4*)(Bp + (size_t)k0 * N);
    }
    __syncthreads();
#pragma unroll
    for (int k = 0; k < 16; ++k) {
      float av[4], bv[4];
      *(float4*)av = *(const float4*)&As[k][ty * 4];
      *(float4*)bv = *(const float4*)&Bs[k][tx * 4];
#pragma unroll
      for (int i = 0; i < 4; ++i)
#pragma unroll
        for (int j = 0; j < 4; ++j) acc[i][j] += av[i] * bv[j];
    }
    __syncthreads();
  }

#pragma unroll
  for (int i = 0; i < 4; ++i) {
    const int row = m0 + ty * 4 + i;
#pragma unroll
    for (int j = 0; j < 4; ++j) {
      const int col = n0 + tx * 4 + j;
      float v = acc[i][j];
      if (BIAS) v += bias[col];
      C[(size_t)row * N + col] = v;
    }
  }
}

// Attention: one wave per (output row t, head). lane = head dim.
// Output row 0 = V(token 0). Row t>=1: grid position i=t-1, query token t,
// keys = BOS (token 0) + neighbors nbr<=i (token nbr+1). Online softmax.
__global__ __launch_bounds__(256) void attn_kernel(const float* __restrict__ qkv,
                                                   float* __restrict__ O) {
  const int t = blockIdx.x;
  const int lane = threadIdx.x & 63;
  const int wave = threadIdx.x >> 6;
  const int head = blockIdx.y * 4 + wave;
  const int hd = head * 64 + lane;

  if (t == 0) {
    O[hd] = qkv[2 * INNER + hd];  // V segment of token 0
    return;
  }

  const int i = t - 1;
  const int f = i >> 10;
  const int hh = (i >> 5) & 31;
  const int ww = i & 31;

  const float q = qkv[(size_t)t * (3 * INNER) + hd] * 0.125f;  // DHEAD^-0.5
  const float* kb = qkv + INNER + hd;       // K[tok] = kb[tok*1536]
  const float* vb = qkv + 2 * INNER + hd;   // V[tok] = vb[tok*1536]

  // BOS (token 0), always unmasked
  float s = q * kb[0];
#pragma unroll
  for (int off = 32; off; off >>= 1) s += __shfl_xor(s, off, 64);
  float m = s, l = 1.0f, acc = vb[0];

  for (int df = -2; df <= 2; ++df) {
    const int ff = f + df;
    if (ff < 0 || ff >= F_) continue;
    for (int dh = -2; dh <= 2; ++dh) {
      const int h2 = hh + dh;
      if ((unsigned)h2 >= (unsigned)H_) continue;
      for (int dw = -2; dw <= 2; ++dw) {
        const int w2 = ww + dw;
        if ((unsigned)w2 >= (unsigned)W_) continue;
        const int nbr = (ff << 10) | (h2 << 5) | w2;
        if (nbr > i) continue;                 // causal: keep nbr <= i
        const size_t toff = (size_t)(nbr + 1) * (3 * INNER);
        float sv = q * kb[toff];
#pragma unroll
        for (int off = 32; off; off >>= 1) sv += __shfl_xor(sv, off, 64);
        const float vv = vb[toff];
        const float mn = fmaxf(m, sv);
        const float p = __expf(sv - mn);
        const float corr = __expf(m - mn);
        l = l * corr + p;
        acc = acc * corr + p * vv;
        m = mn;
      }
    }
  }
  O[(size_t)t * INNER + hd] = acc / l;
}

extern "C" void kernel_launch(void* const* d_in, const int* in_sizes, int n_in,
                              void* d_out, int out_size, void* d_ws, size_t ws_size,
                              hipStream_t stream) {
  const float* x     = (const float*)d_in[0];
  const float* w_qkv = (const float*)d_in[1];
  const float* w_out = (const float*)d_in[2];
  const float* b_out = (const float*)d_in[3];
  float* out = (float*)d_out;

  float* qkv = (float*)d_ws;                      // 2048 x 1536 fp32
  float* O   = qkv + (size_t)NTOK * 3 * INNER;    // 2048 x 512  fp32

  // 1) qkv = x @ w_qkv   (M=2048, N=1536, K=512)
  hipLaunchKernelGGL((gemm_tile<false>),
                     dim3(1536 / 64, NTOK / 64), dim3(256), 0, stream,
                     x, w_qkv, nullptr, qkv, NTOK, 3 * INNER, INNER);

  // 2) windowed causal attention -> O (fp32)
  hipLaunchKernelGGL(attn_kernel, dim3(NTOK, 2), dim3(256), 0, stream, qkv, O);

  // 3) out = O @ w_out + b_out  (M=2048, N=512, K=512)
  hipLaunchKernelGGL((gemm_tile<true>),
                     dim3(INNER / 64, NTOK / 64), dim3(256), 0, stream,
                     O, w_out, b_out, out, NTOK, INNER, INNER);
}

// Round 3
// 134.189 us; speedup vs baseline: 1.3094x; 1.3094x over previous
//
#include <hip/hip_runtime.h>
#include <hip/hip_bf16.h>

// Problem constants
#define F_    2
#define H_    32
#define W_    32
#define NTOK  2048          // F_*H_*W_
#define INNER 512           // HEADS*DHEAD
#define HEADS 8
#define DHEAD 64
#define KDIM  512           // contraction dim for both GEMMs

typedef __attribute__((ext_vector_type(8))) short bf16x8;
typedef __attribute__((ext_vector_type(4))) float f32x4;

// fp32 -> bf16 bits, round-to-nearest-even (finite inputs only)
__device__ __forceinline__ unsigned short f2b(float f) {
  unsigned int u = __float_as_uint(f);
  return (unsigned short)((u + 0x7FFFu + ((u >> 16) & 1u)) >> 16);
}

// ---------------- conversion kernels ----------------

// fp32[n] -> bf16[n], 4 elems/thread
__global__ __launch_bounds__(256) void cvt_bf16(const float* __restrict__ in,
                                                unsigned short* __restrict__ out, int n) {
  int i = (blockIdx.x * 256 + threadIdx.x) * 4;
  if (i >= n) return;
  float4 v = *(const float4*)(in + i);
  ushort4 o;
  o.x = f2b(v.x); o.y = f2b(v.y); o.z = f2b(v.z); o.w = f2b(v.w);
  *(ushort4*)(out + i) = o;
}

// in: [K][N] fp32  ->  out: [N][K] bf16 (transpose + convert). K,N multiples of 32.
__global__ __launch_bounds__(256) void transpose_cvt(const float* __restrict__ in,
                                                     unsigned short* __restrict__ out,
                                                     int K, int N) {
  __shared__ float tile[32][33];
  const int k0 = blockIdx.y * 32;
  const int n0 = blockIdx.x * 32;
  const int r  = threadIdx.x >> 3;
  const int c4 = (threadIdx.x & 7) * 4;
  float4 v = *(const float4*)(in + (size_t)(k0 + r) * N + n0 + c4);
  tile[r][c4 + 0] = v.x; tile[r][c4 + 1] = v.y;
  tile[r][c4 + 2] = v.z; tile[r][c4 + 3] = v.w;
  __syncthreads();
  ushort4 o;
  o.x = f2b(tile[c4 + 0][r]);
  o.y = f2b(tile[c4 + 1][r]);
  o.z = f2b(tile[c4 + 2][r]);
  o.w = f2b(tile[c4 + 3][r]);
  *(ushort4*)(out + (size_t)(n0 + r) * K + k0 + c4) = o;
}

// ---------------- MFMA bf16 GEMM ----------------
// C[M][N] = A[M][K] * Bt[N][K]^T (+bias). M%128==0, N%128==0, K%32==0.
// A, Bt are bf16 bits; C fp32. 128x128 tile, BK=32, 4 waves (2x2 of 64x64).
template <bool BIAS>
__global__ __launch_bounds__(256) void gemm_mfma(const unsigned short* __restrict__ A,
                                                 const unsigned short* __restrict__ Bt,
                                                 const float* __restrict__ bias,
                                                 float* __restrict__ C,
                                                 int M, int N, int K) {
  constexpr int BM = 128, BN = 128, BK = 32;
  __shared__ __align__(16) unsigned short As[BM * BK];
  __shared__ __align__(16) unsigned short Bs[BN * BK];

  const int tid  = threadIdx.x;
  const int lane = tid & 63;
  const int wave = tid >> 6;
  const int m0 = blockIdx.y * BM;
  const int n0 = blockIdx.x * BN;
  const int wm = (wave >> 1) * 64;  // wave tile origin inside block tile
  const int wn = (wave & 1) * 64;

  // staging indices: each thread moves 8 bf16 (16B) per pass, 2 passes per tile
  const int li0 = tid * 8;            // pass 0 linear elem index
  const int li1 = (256 + tid) * 8;    // pass 1
  const int r0 = li0 >> 5, c0 = li0 & 31;
  const int r1 = li1 >> 5, c1 = li1 & 31;

  const int fr = lane & 15;           // fragment row index (m or n)
  const int fk = (lane >> 4) * 8;     // fragment k offset

  f32x4 acc[4][4] = {};

  for (int k0 = 0; k0 < K; k0 += BK) {
    // stage A tile [BM][BK] and Bt tile [BN][BK], both k-contiguous
    *(bf16x8*)&As[r0 * BK + c0] = *(const bf16x8*)(A + (size_t)(m0 + r0) * K + k0 + c0);
    *(bf16x8*)&As[r1 * BK + c1] = *(const bf16x8*)(A + (size_t)(m0 + r1) * K + k0 + c1);
    *(bf16x8*)&Bs[r0 * BK + c0] = *(const bf16x8*)(Bt + (size_t)(n0 + r0) * K + k0 + c0);
    *(bf16x8*)&Bs[r1 * BK + c1] = *(const bf16x8*)(Bt + (size_t)(n0 + r1) * K + k0 + c1);
    __syncthreads();

    bf16x8 af[4], bf[4];
#pragma unroll
    for (int i = 0; i < 4; ++i)
      af[i] = *(const bf16x8*)&As[(wm + i * 16 + fr) * BK + fk];
#pragma unroll
    for (int j = 0; j < 4; ++j)
      bf[j] = *(const bf16x8*)&Bs[(wn + j * 16 + fr) * BK + fk];

#pragma unroll
    for (int i = 0; i < 4; ++i)
#pragma unroll
      for (int j = 0; j < 4; ++j)
        acc[i][j] = __builtin_amdgcn_mfma_f32_16x16x32_bf16(af[i], bf[j], acc[i][j], 0, 0, 0);
    __syncthreads();
  }

  // epilogue: C/D layout col=lane&15, row=(lane>>4)*4+reg
  const int er = (lane >> 4) * 4;
  const int ec = lane & 15;
#pragma unroll
  for (int i = 0; i < 4; ++i) {
#pragma unroll
    for (int j = 0; j < 4; ++j) {
      const int col = n0 + wn + j * 16 + ec;
      float b = BIAS ? bias[col] : 0.0f;
#pragma unroll
      for (int r = 0; r < 4; ++r) {
        const int row = m0 + wm + i * 16 + er + r;
        C[(size_t)row * N + col] = acc[i][j][r] + b;
      }
    }
  }
}

// ---------------- attention ----------------
// One wave per (output row t, head). lane = head dim. Online softmax, fp32.
// Writes O as bf16 (A-operand of the out GEMM).
__global__ __launch_bounds__(256) void attn_kernel(const float* __restrict__ qkv,
                                                   unsigned short* __restrict__ O) {
  const int t = blockIdx.x;
  const int lane = threadIdx.x & 63;
  const int wave = threadIdx.x >> 6;
  const int head = blockIdx.y * 4 + wave;
  const int hd = head * 64 + lane;

  if (t == 0) {
    O[hd] = f2b(qkv[2 * INNER + hd]);  // V segment of token 0
    return;
  }

  const int i = t - 1;
  const int f = i >> 10;
  const int hh = (i >> 5) & 31;
  const int ww = i & 31;

  const float q = qkv[(size_t)t * (3 * INNER) + hd] * 0.125f;  // DHEAD^-0.5
  const float* kb = qkv + INNER + hd;       // K[tok] = kb[tok*1536]
  const float* vb = qkv + 2 * INNER + hd;   // V[tok] = vb[tok*1536]

  // BOS (token 0), always unmasked
  float s = q * kb[0];
#pragma unroll
  for (int off = 32; off; off >>= 1) s += __shfl_xor(s, off, 64);
  float m = s, l = 1.0f, acc = vb[0];

  for (int df = -2; df <= 2; ++df) {
    const int ff = f + df;
    if (ff < 0 || ff >= F_) continue;
    for (int dh = -2; dh <= 2; ++dh) {
      const int h2 = hh + dh;
      if ((unsigned)h2 >= (unsigned)H_) continue;
      for (int dw = -2; dw <= 2; ++dw) {
        const int w2 = ww + dw;
        if ((unsigned)w2 >= (unsigned)W_) continue;
        const int nbr = (ff << 10) | (h2 << 5) | w2;
        if (nbr > i) continue;                 // causal: keep nbr <= i
        const size_t toff = (size_t)(nbr + 1) * (3 * INNER);
        float sv = q * kb[toff];
#pragma unroll
        for (int off = 32; off; off >>= 1) sv += __shfl_xor(sv, off, 64);
        const float vv = vb[toff];
        const float mn = fmaxf(m, sv);
        const float p = __expf(sv - mn);
        const float corr = __expf(m - mn);
        l = l * corr + p;
        acc = acc * corr + p * vv;
        m = mn;
      }
    }
  }
  O[(size_t)t * INNER + hd] = f2b(acc / l);
}

// ---------------- launch ----------------

extern "C" void kernel_launch(void* const* d_in, const int* in_sizes, int n_in,
                              void* d_out, int out_size, void* d_ws, size_t ws_size,
                              hipStream_t stream) {
  const float* x     = (const float*)d_in[0];
  const float* w_qkv = (const float*)d_in[1];
  const float* w_out = (const float*)d_in[2];
  const float* b_out = (const float*)d_in[3];
  float* out = (float*)d_out;

  char* ws = (char*)d_ws;
  float*          qkv   = (float*)(ws);                       // 2048x1536 fp32   (12.58 MB)
  unsigned short* xb    = (unsigned short*)(ws + 12582912);   // 2048x512  bf16   (2 MB)
  unsigned short* wqkvT = (unsigned short*)(ws + 14680064);   // 1536x512  bf16   (1.5 MB)
  unsigned short* woutT = (unsigned short*)(ws + 16252928);   // 512x512   bf16   (0.5 MB)
  unsigned short* Ob    = (unsigned short*)(ws + 16777216);   // 2048x512  bf16   (2 MB)

  // convert inputs to bf16 (weights transposed to [N][K])
  hipLaunchKernelGGL(cvt_bf16, dim3((NTOK * INNER) / 1024), dim3(256), 0, stream,
                     x, xb, NTOK * INNER);
  hipLaunchKernelGGL(transpose_cvt, dim3((3 * INNER) / 32, KDIM / 32), dim3(256), 0, stream,
                     w_qkv, wqkvT, KDIM, 3 * INNER);
  hipLaunchKernelGGL(transpose_cvt, dim3(INNER / 32, KDIM / 32), dim3(256), 0, stream,
                     w_out, woutT, KDIM, INNER);

  // 1) qkv = x @ w_qkv   (M=2048, N=1536, K=512) via MFMA
  hipLaunchKernelGGL((gemm_mfma<false>), dim3((3 * INNER) / 128, NTOK / 128), dim3(256), 0, stream,
                     xb, wqkvT, nullptr, qkv, NTOK, 3 * INNER, KDIM);

  // 2) windowed causal attention -> O bf16
  hipLaunchKernelGGL(attn_kernel, dim3(NTOK, 2), dim3(256), 0, stream, qkv, Ob);

  // 3) out = O @ w_out + b_out  (M=2048, N=512, K=512) via MFMA
  hipLaunchKernelGGL((gemm_mfma<true>), dim3(INNER / 128, NTOK / 128), dim3(256), 0, stream,
                     Ob, woutT, b_out, out, NTOK, INNER, KDIM);
}

// Round 4
// 113.437 us; speedup vs baseline: 1.5489x; 1.1829x over previous
//
#include <hip/hip_runtime.h>
#include <hip/hip_bf16.h>

// Problem constants
#define NTOK  2048          // F*H*W = 2*32*32
#define INNER 512
#define HEADS 8
#define KDIM  512
#define QKVP  1536          // qkv row pitch in bf16 elements (Q|K|V)

typedef __attribute__((ext_vector_type(8))) short bf16x8;
typedef __attribute__((ext_vector_type(4))) float f32x4;

// fp32 -> bf16 bits, round-to-nearest-even (finite inputs only)
__device__ __forceinline__ unsigned short f2b(float f) {
  unsigned int u = __float_as_uint(f);
  return (unsigned short)((u + 0x7FFFu + ((u >> 16) & 1u)) >> 16);
}

__device__ __forceinline__ void storeC(float* p, float v) { *p = v; }
__device__ __forceinline__ void storeC(unsigned short* p, float v) { *p = f2b(v); }

// ---------------- conversion kernels ----------------

__global__ __launch_bounds__(256) void cvt_bf16(const float* __restrict__ in,
                                                unsigned short* __restrict__ out, int n) {
  int i = (blockIdx.x * 256 + threadIdx.x) * 4;
  if (i >= n) return;
  float4 v = *(const float4*)(in + i);
  ushort4 o;
  o.x = f2b(v.x); o.y = f2b(v.y); o.z = f2b(v.z); o.w = f2b(v.w);
  *(ushort4*)(out + i) = o;
}

// in: [K][N] fp32 -> out: [N][K] bf16
__global__ __launch_bounds__(256) void transpose_cvt(const float* __restrict__ in,
                                                     unsigned short* __restrict__ out,
                                                     int K, int N) {
  __shared__ float tile[32][33];
  const int k0 = blockIdx.y * 32;
  const int n0 = blockIdx.x * 32;
  const int r  = threadIdx.x >> 3;
  const int c4 = (threadIdx.x & 7) * 4;
  float4 v = *(const float4*)(in + (size_t)(k0 + r) * N + n0 + c4);
  tile[r][c4 + 0] = v.x; tile[r][c4 + 1] = v.y;
  tile[r][c4 + 2] = v.z; tile[r][c4 + 3] = v.w;
  __syncthreads();
  ushort4 o;
  o.x = f2b(tile[c4 + 0][r]);
  o.y = f2b(tile[c4 + 1][r]);
  o.z = f2b(tile[c4 + 2][r]);
  o.w = f2b(tile[c4 + 3][r]);
  *(ushort4*)(out + (size_t)(n0 + r) * K + k0 + c4) = o;
}

// ---------------- MFMA bf16 GEMM ----------------
// C[M][N] = A[M][K] * Bt[N][K]^T (+bias). 128x128 tile, BK=32, 4 waves.
template <bool BIAS, typename TC>
__global__ __launch_bounds__(256) void gemm_mfma(const unsigned short* __restrict__ A,
                                                 const unsigned short* __restrict__ Bt,
                                                 const float* __restrict__ bias,
                                                 TC* __restrict__ C,
                                                 int M, int N, int K) {
  constexpr int BM = 128, BN = 128, BK = 32;
  __shared__ __align__(16) unsigned short As[BM * BK];
  __shared__ __align__(16) unsigned short Bs[BN * BK];

  const int tid  = threadIdx.x;
  const int lane = tid & 63;
  const int wave = tid >> 6;
  const int m0 = blockIdx.y * BM;
  const int n0 = blockIdx.x * BN;
  const int wm = (wave >> 1) * 64;
  const int wn = (wave & 1) * 64;

  const int li0 = tid * 8;
  const int li1 = (256 + tid) * 8;
  const int r0 = li0 >> 5, c0 = li0 & 31;
  const int r1 = li1 >> 5, c1 = li1 & 31;

  const int fr = lane & 15;
  const int fk = (lane >> 4) * 8;

  f32x4 acc[4][4] = {};

  for (int k0 = 0; k0 < K; k0 += BK) {
    *(bf16x8*)&As[r0 * BK + c0] = *(const bf16x8*)(A + (size_t)(m0 + r0) * K + k0 + c0);
    *(bf16x8*)&As[r1 * BK + c1] = *(const bf16x8*)(A + (size_t)(m0 + r1) * K + k0 + c1);
    *(bf16x8*)&Bs[r0 * BK + c0] = *(const bf16x8*)(Bt + (size_t)(n0 + r0) * K + k0 + c0);
    *(bf16x8*)&Bs[r1 * BK + c1] = *(const bf16x8*)(Bt + (size_t)(n0 + r1) * K + k0 + c1);
    __syncthreads();

    bf16x8 af[4], bfr[4];
#pragma unroll
    for (int i = 0; i < 4; ++i)
      af[i] = *(const bf16x8*)&As[(wm + i * 16 + fr) * BK + fk];
#pragma unroll
    for (int j = 0; j < 4; ++j)
      bfr[j] = *(const bf16x8*)&Bs[(wn + j * 16 + fr) * BK + fk];

#pragma unroll
    for (int i = 0; i < 4; ++i)
#pragma unroll
      for (int j = 0; j < 4; ++j)
        acc[i][j] = __builtin_amdgcn_mfma_f32_16x16x32_bf16(af[i], bfr[j], acc[i][j], 0, 0, 0);
    __syncthreads();
  }

  const int er = (lane >> 4) * 4;
  const int ec = lane & 15;
#pragma unroll
  for (int i = 0; i < 4; ++i) {
#pragma unroll
    for (int j = 0; j < 4; ++j) {
      const int col = n0 + wn + j * 16 + ec;
      float b = BIAS ? bias[col] : 0.0f;
#pragma unroll
      for (int r = 0; r < 4; ++r) {
        const int row = m0 + wm + i * 16 + er + r;
        storeC(&C[(size_t)row * N + col], acc[i][j][r] + b);
      }
    }
  }
}

// ---------------- MFMA flash attention ----------------
// Q-tile = 16 consecutive w-positions (same f, h). Block = (tile pt, head-group),
// 4 waves = 4 heads, each wave independent. Packed causal key list in LDS
// (slot 0 = BOS, guaranteeing finite m after subtile 0 for every query).
// S^T = K*Q^T via mfma (C row = key slot, col = query), so P^T is directly the
// PV B-operand (keys quad*4+j at k-slots quad*8+j, upper half zero-padded).
__global__ __launch_bounds__(256) void attn_mfma(const unsigned short* __restrict__ qkv,
                                                 unsigned short* __restrict__ O) {
  __shared__ __align__(16) int list[192];
  __shared__ int cntS;
  const int tid = threadIdx.x;
  const int hg = blockIdx.y;

  if (blockIdx.x == 128) {  // output row 0 = V(token 0), bf16 copy
    O[hg * 256 + tid] = qkv[1024 + hg * 256 + tid];
    return;
  }
  const int pt = blockIdx.x;
  const int f  = pt >> 6;
  const int hh = (pt >> 1) & 31;
  const int w0 = (pt & 1) << 4;
  const int base_i = (f << 10) | (hh << 5) | w0;

  // --- build packed key list (tokens; 0=BOS, 0x7FFFFFFF=pad) ---
  if (tid < 192) list[tid] = 0x7FFFFFFF;
  if (tid == 0) { list[0] = 0; cntS = 1; }
  __syncthreads();
  if (tid >= 1 && tid <= 160) {
    int c = tid - 1;
    int p = c / 20, wo = c - p * 20;
    int ff = (p < 5) ? 0 : 1;
    int h2 = hh - 2 + ((p < 5) ? p : (p - 5));
    // (ff,h2) lexicographically <= (f,hh): ff<f full h-range, ff==f needs h2<=hh
    bool ok = (p < 5) ? ((f == 1) ? (h2 >= 0 && h2 <= 31) : (p <= 2 && h2 >= 0))
                      : (f == 1 && h2 >= 0);
    if (ok) {
      bool diag = (ff == f) && (h2 == hh);
      int wlo = max(0, w0 - 2);
      int whi = min(31, diag ? (w0 + 15) : (w0 + 17));
      int w2 = wlo + wo;
      if (w2 <= whi) {
        int pos = atomicAdd(&cntS, 1);
        list[pos] = ((ff << 10) | (h2 << 5) | w2) + 1;
      }
    }
  }
  __syncthreads();
  const int cnt  = cntS;
  const int nsub = (cnt + 15) >> 4;

  const int lane = tid & 63;
  const int wave = tid >> 6;
  const int head = hg * 4 + wave;
  const int quad = lane >> 4;
  const int ec   = lane & 15;

  const int i_q = base_i + ec;          // this lane's query grid index (column)
  const int tq  = min(i_q + 1, 2047);   // i=2047's output is dropped; clamp read
  const unsigned short* qrow = qkv + (size_t)tq * QKVP + head * 64 + quad * 8;
  const bf16x8 qb0 = *(const bf16x8*)(qrow);        // B-frag: n=query, k=d 0..31
  const bf16x8 qb1 = *(const bf16x8*)(qrow + 32);   // d 32..63

  f32x4 Od[4] = {{0,0,0,0},{0,0,0,0},{0,0,0,0},{0,0,0,0}};  // dims dt*16+quad*4+r, query ec
  float m = -1e30f, l = 0.0f;

  for (int sub = 0; sub < nsub; ++sub) {
    const int base = sub * 16;
    const int tok_e = list[base + ec];                    // A-frag row token (key slot = ec)
    const int4 tokv = *(const int4*)&list[base + quad * 4];  // my quad's 4 key slots
    const int tk[4] = {tokv.x, tokv.y, tokv.z, tokv.w};

    // S^T = K * Q^T : C row = key slot (quad*4+r), col = query (ec)
    f32x4 S = {0, 0, 0, 0};
    {
      const int t0 = (tok_e > 2047) ? 0 : tok_e;
      const unsigned short* kr = qkv + (size_t)t0 * QKVP + 512 + head * 64 + quad * 8;
      const bf16x8 kf0 = *(const bf16x8*)(kr);
      const bf16x8 kf1 = *(const bf16x8*)(kr + 32);
      S = __builtin_amdgcn_mfma_f32_16x16x32_bf16(kf0, qb0, S, 0, 0, 0);
      S = __builtin_amdgcn_mfma_f32_16x16x32_bf16(kf1, qb1, S, 0, 0, 0);
    }

    // mask + scale (window |dw|<=2 and causal idx<=i_q; BOS always valid;
    // pad sentinel fails idx<=i_q). Masked -> -1e30 -> exp()=0 since m finite.
    float Sm[4];
#pragma unroll
    for (int r = 0; r < 4; ++r) {
      const int tok = tk[r];
      const int idx = tok - 1;
      const bool v = (tok == 0) ||
                     ((idx <= i_q) && ((unsigned)((idx & 31) - (w0 + ec) + 2) <= 4u));
      Sm[r] = v ? S[r] * 0.125f : -1e30f;
    }
    // key-reduction for this query: 4 regs + quads (xor 16, 32)
    float mx = fmaxf(fmaxf(Sm[0], Sm[1]), fmaxf(Sm[2], Sm[3]));
    mx = fmaxf(mx, __shfl_xor(mx, 16, 64));
    mx = fmaxf(mx, __shfl_xor(mx, 32, 64));
    const float mn = fmaxf(m, mx);
    const float corr = __expf(m - mn);
    m = mn;
    const float p0 = __expf(Sm[0] - mn);
    const float p1 = __expf(Sm[1] - mn);
    const float p2 = __expf(Sm[2] - mn);
    const float p3 = __expf(Sm[3] - mn);
    float rs = (p0 + p1) + (p2 + p3);
    rs += __shfl_xor(rs, 16, 64);
    rs += __shfl_xor(rs, 32, 64);
    l = l * corr + rs;

    // PV B-frag: P^T at k-slots quad*8+{0..3}, zeros at {4..7}
    bf16x8 pf;
    pf[0] = (short)f2b(p0); pf[1] = (short)f2b(p1);
    pf[2] = (short)f2b(p2); pf[3] = (short)f2b(p3);
    pf[4] = 0; pf[5] = 0; pf[6] = 0; pf[7] = 0;

    const unsigned short* vp[4];
#pragma unroll
    for (int j = 0; j < 4; ++j) {
      const int tv = (tk[j] > 2047) ? 0 : tk[j];
      vp[j] = qkv + (size_t)tv * QKVP + 1024 + head * 64 + ec;
    }
#pragma unroll
    for (int dt = 0; dt < 4; ++dt) {
      bf16x8 vf;  // A-frag: V^T, m = dim-in-tile (ec), k-slots quad*8+j -> key quad*4+j
#pragma unroll
      for (int j = 0; j < 4; ++j) vf[j] = (short)vp[j][dt * 16];
      vf[4] = 0; vf[5] = 0; vf[6] = 0; vf[7] = 0;
#pragma unroll
      for (int r = 0; r < 4; ++r) Od[dt][r] *= corr;
      Od[dt] = __builtin_amdgcn_mfma_f32_16x16x32_bf16(vf, pf, Od[dt], 0, 0, 0);
    }
  }

  if (i_q <= 2046) {
    const float rl = 1.0f / l;
    unsigned short* ob = O + (size_t)(i_q + 1) * 512 + head * 64 + quad * 4;
#pragma unroll
    for (int dt = 0; dt < 4; ++dt) {
      ushort4 u;
      u.x = f2b(Od[dt][0] * rl);
      u.y = f2b(Od[dt][1] * rl);
      u.z = f2b(Od[dt][2] * rl);
      u.w = f2b(Od[dt][3] * rl);
      *(ushort4*)(ob + dt * 16) = u;
    }
  }
}

// ---------------- launch ----------------

extern "C" void kernel_launch(void* const* d_in, const int* in_sizes, int n_in,
                              void* d_out, int out_size, void* d_ws, size_t ws_size,
                              hipStream_t stream) {
  const float* x     = (const float*)d_in[0];
  const float* w_qkv = (const float*)d_in[1];
  const float* w_out = (const float*)d_in[2];
  const float* b_out = (const float*)d_in[3];
  float* out = (float*)d_out;

  char* ws = (char*)d_ws;
  unsigned short* qkvb  = (unsigned short*)(ws);             // 2048x1536 bf16 (6.29 MB)
  unsigned short* xb    = (unsigned short*)(ws + 6291456);   // 2048x512
  unsigned short* wqkvT = (unsigned short*)(ws + 8388608);   // 1536x512
  unsigned short* woutT = (unsigned short*)(ws + 9961472);   // 512x512
  unsigned short* Ob    = (unsigned short*)(ws + 10485760);  // 2048x512

  hipLaunchKernelGGL(cvt_bf16, dim3((NTOK * INNER) / 1024), dim3(256), 0, stream,
                     x, xb, NTOK * INNER);
  hipLaunchKernelGGL(transpose_cvt, dim3((3 * INNER) / 32, KDIM / 32), dim3(256), 0, stream,
                     w_qkv, wqkvT, KDIM, 3 * INNER);
  hipLaunchKernelGGL(transpose_cvt, dim3(INNER / 32, KDIM / 32), dim3(256), 0, stream,
                     w_out, woutT, KDIM, INNER);

  // 1) qkv = x @ w_qkv  -> bf16 (M=2048, N=1536, K=512)
  hipLaunchKernelGGL((gemm_mfma<false, unsigned short>),
                     dim3((3 * INNER) / 128, NTOK / 128), dim3(256), 0, stream,
                     xb, wqkvT, nullptr, qkvb, NTOK, 3 * INNER, KDIM);

  // 2) MFMA flash attention -> Ob bf16
  hipLaunchKernelGGL(attn_mfma, dim3(129, 2), dim3(256), 0, stream, qkvb, Ob);

  // 3) out = O @ w_out + b_out (M=2048, N=512, K=512) -> fp32
  hipLaunchKernelGGL((gemm_mfma<true, float>),
                     dim3(INNER / 128, NTOK / 128), dim3(256), 0, stream,
                     Ob, woutT, b_out, out, NTOK, INNER, KDIM);
}

// Round 5
// 98.380 us; speedup vs baseline: 1.7860x; 1.1530x over previous
//
#include <hip/hip_runtime.h>
#include <hip/hip_bf16.h>

#define NTOK  2048          // F*H*W = 2*32*32
#define INNER 512
#define KDIM  512
#define QKVP  1536          // qkv row pitch (bf16 elems)

typedef __attribute__((ext_vector_type(8))) short bf16x8;
typedef __attribute__((ext_vector_type(4))) float f32x4;

// fp32 -> bf16 bits, round-to-nearest-even
__device__ __forceinline__ unsigned short f2b(float f) {
  unsigned int u = __float_as_uint(f);
  return (unsigned short)((u + 0x7FFFu + ((u >> 16) & 1u)) >> 16);
}

// ---------------- prep: transpose+convert both weights ----------------
// w_qkv [512][1536] -> wqkvT [1536][512] bf16 ; w_out [512][512] -> woutT [512][512] bf16
__global__ __launch_bounds__(256) void prep_w(const float* __restrict__ w_qkv,
                                              const float* __restrict__ w_out,
                                              unsigned short* __restrict__ wqkvT,
                                              unsigned short* __restrict__ woutT) {
  __shared__ float tile[32][33];
  int b = blockIdx.x;
  const float* in; unsigned short* out; int K, N, bx, by;
  if (b < 768) { in = w_qkv; out = wqkvT; K = 512; N = 1536; bx = b % 48; by = b / 48; }
  else { b -= 768; in = w_out; out = woutT; K = 512; N = 512; bx = b & 15; by = b >> 4; }
  const int k0 = by * 32, n0 = bx * 32;
  const int r = threadIdx.x >> 3, c4 = (threadIdx.x & 7) * 4;
  float4 v = *(const float4*)(in + (size_t)(k0 + r) * N + n0 + c4);
  tile[r][c4 + 0] = v.x; tile[r][c4 + 1] = v.y;
  tile[r][c4 + 2] = v.z; tile[r][c4 + 3] = v.w;
  __syncthreads();
  ushort4 o;
  o.x = f2b(tile[c4 + 0][r]);
  o.y = f2b(tile[c4 + 1][r]);
  o.z = f2b(tile[c4 + 2][r]);
  o.w = f2b(tile[c4 + 3][r]);
  *(ushort4*)(out + (size_t)(n0 + r) * K + k0 + c4) = o;
}

// ---------------- GEMM1: qkv = x(fp32) @ wqkvT^T -> bf16 ----------------
// BM=64, BN=128, BK=32; 384 blocks; x converted to bf16 in-register during staging.
__global__ __launch_bounds__(256, 2) void gemm_qkv(const float* __restrict__ x,
                                                   const unsigned short* __restrict__ Bt,
                                                   unsigned short* __restrict__ C) {
  constexpr int BM = 64, BN = 128, BK = 32, N = 1536, K = 512;
  __shared__ __align__(16) unsigned short As[BM * BK];
  __shared__ __align__(16) unsigned short Bs[BN * BK];
  const int tid = threadIdx.x, lane = tid & 63, wave = tid >> 6;
  const int m0 = blockIdx.y * BM, n0 = blockIdx.x * BN;
  const int wm = (wave >> 1) * 32, wn = (wave & 1) * 64;
  const int ar = tid >> 2, ac = (tid & 3) * 8;            // A: 64x32, 8 elems/thread
  const int li0 = tid * 8, li1 = (256 + tid) * 8;         // B: 128x32, 16 elems/thread
  const int br0 = li0 >> 5, bc0 = li0 & 31;
  const int br1 = li1 >> 5, bc1 = li1 & 31;
  const int fr = lane & 15, fk = (lane >> 4) * 8;

  f32x4 acc[2][4] = {};

  for (int k0 = 0; k0 < K; k0 += BK) {
    float4 a0 = *(const float4*)(x + (size_t)(m0 + ar) * K + k0 + ac);
    float4 a1 = *(const float4*)(x + (size_t)(m0 + ar) * K + k0 + ac + 4);
    bf16x8 av;
    av[0] = (short)f2b(a0.x); av[1] = (short)f2b(a0.y);
    av[2] = (short)f2b(a0.z); av[3] = (short)f2b(a0.w);
    av[4] = (short)f2b(a1.x); av[5] = (short)f2b(a1.y);
    av[6] = (short)f2b(a1.z); av[7] = (short)f2b(a1.w);
    *(bf16x8*)&As[ar * BK + ac] = av;
    *(bf16x8*)&Bs[li0] = *(const bf16x8*)(Bt + (size_t)(n0 + br0) * K + k0 + bc0);
    *(bf16x8*)&Bs[li1] = *(const bf16x8*)(Bt + (size_t)(n0 + br1) * K + k0 + bc1);
    __syncthreads();

    bf16x8 af[2], bfr[4];
#pragma unroll
    for (int i = 0; i < 2; ++i) af[i] = *(const bf16x8*)&As[(wm + i * 16 + fr) * BK + fk];
#pragma unroll
    for (int j = 0; j < 4; ++j) bfr[j] = *(const bf16x8*)&Bs[(wn + j * 16 + fr) * BK + fk];
#pragma unroll
    for (int i = 0; i < 2; ++i)
#pragma unroll
      for (int j = 0; j < 4; ++j)
        acc[i][j] = __builtin_amdgcn_mfma_f32_16x16x32_bf16(af[i], bfr[j], acc[i][j], 0, 0, 0);
    __syncthreads();
  }

  const int er = (lane >> 4) * 4, ec = lane & 15;
#pragma unroll
  for (int i = 0; i < 2; ++i)
#pragma unroll
    for (int j = 0; j < 4; ++j) {
      const int col = n0 + wn + j * 16 + ec;
#pragma unroll
      for (int r = 0; r < 4; ++r) {
        const int row = m0 + wm + i * 16 + er + r;
        C[(size_t)row * N + col] = f2b(acc[i][j][r]);
      }
    }
}

// ---------------- GEMM2: out = Ob @ woutT^T + bias -> fp32 ----------------
// BM=64, BN=64, BK=32; 256 blocks.
__global__ __launch_bounds__(256, 2) void gemm_out(const unsigned short* __restrict__ A,
                                                   const unsigned short* __restrict__ Bt,
                                                   const float* __restrict__ bias,
                                                   float* __restrict__ C) {
  constexpr int BM = 64, BN = 64, BK = 32, N = 512, K = 512;
  __shared__ __align__(16) unsigned short As[BM * BK];
  __shared__ __align__(16) unsigned short Bs[BN * BK];
  const int tid = threadIdx.x, lane = tid & 63, wave = tid >> 6;
  const int m0 = blockIdx.y * BM, n0 = blockIdx.x * BN;
  const int wm = (wave >> 1) * 32, wn = (wave & 1) * 32;
  const int r = tid >> 2, c = (tid & 3) * 8, li = tid * 8;
  const int fr = lane & 15, fk = (lane >> 4) * 8;

  f32x4 acc[2][2] = {};

  for (int k0 = 0; k0 < K; k0 += BK) {
    *(bf16x8*)&As[li] = *(const bf16x8*)(A + (size_t)(m0 + r) * K + k0 + c);
    *(bf16x8*)&Bs[li] = *(const bf16x8*)(Bt + (size_t)(n0 + r) * K + k0 + c);
    __syncthreads();
    bf16x8 af[2], bfr[2];
#pragma unroll
    for (int i = 0; i < 2; ++i) af[i] = *(const bf16x8*)&As[(wm + i * 16 + fr) * BK + fk];
#pragma unroll
    for (int j = 0; j < 2; ++j) bfr[j] = *(const bf16x8*)&Bs[(wn + j * 16 + fr) * BK + fk];
#pragma unroll
    for (int i = 0; i < 2; ++i)
#pragma unroll
      for (int j = 0; j < 2; ++j)
        acc[i][j] = __builtin_amdgcn_mfma_f32_16x16x32_bf16(af[i], bfr[j], acc[i][j], 0, 0, 0);
    __syncthreads();
  }

  const int er = (lane >> 4) * 4, ec = lane & 15;
#pragma unroll
  for (int i = 0; i < 2; ++i)
#pragma unroll
    for (int j = 0; j < 2; ++j) {
      const int col = n0 + wn + j * 16 + ec;
      const float b = bias[col];
#pragma unroll
      for (int rr = 0; rr < 4; ++rr) {
        const int row = m0 + wm + i * 16 + er + rr;
        C[(size_t)row * N + col] = acc[i][j][rr] + b;
      }
    }
}

// ---------------- MFMA flash attention, key-split ----------------
// Block = (16-pos tile, head-group). 512 threads = 8 waves = 4 heads x 2 key-halves.
// Half h processes subtiles h, h+2, ... ; results merged via LDS online-softmax
// combine. BOS is in subtile 0 (half 0), so half-0's m is always finite.
__global__ __launch_bounds__(512) void attn_mfma(const unsigned short* __restrict__ qkv,
                                                 unsigned short* __restrict__ O) {
  __shared__ __align__(16) int list[192];
  __shared__ int cntS;
  __shared__ __align__(16) float mOd[4][16][72];  // [headInGrp][query][dim], pad 72
  __shared__ float mM[4][16], mL[4][16];

  const int tid = threadIdx.x;
  const int hg = blockIdx.y;

  if (blockIdx.x == 128) {  // output row 0 = V(token 0)
    if (tid < 256) O[hg * 256 + tid] = qkv[1024 + hg * 256 + tid];
    return;
  }
  const int pt = blockIdx.x;
  const int f  = pt >> 6;
  const int hh = (pt >> 1) & 31;
  const int w0 = (pt & 1) << 4;
  const int base_i = (f << 10) | (hh << 5) | w0;

  if (tid < 192) list[tid] = 0x7FFFFFFF;
  if (tid == 0) { list[0] = 0; cntS = 1; }
  __syncthreads();
  if (tid >= 1 && tid <= 160) {
    int cc = tid - 1;
    int p = cc / 20, wo = cc - p * 20;
    int ff = (p < 5) ? 0 : 1;
    int h2 = hh - 2 + ((p < 5) ? p : (p - 5));
    bool ok = (p < 5) ? ((f == 1) ? (h2 >= 0 && h2 <= 31) : (p <= 2 && h2 >= 0))
                      : (f == 1 && h2 >= 0);
    if (ok) {
      bool diag = (ff == f) && (h2 == hh);
      int wlo = max(0, w0 - 2);
      int whi = min(31, diag ? (w0 + 15) : (w0 + 17));
      int w2 = wlo + wo;
      if (w2 <= whi) {
        int pos = atomicAdd(&cntS, 1);
        list[pos] = ((ff << 10) | (h2 << 5) | w2) + 1;
      }
    }
  }
  __syncthreads();
  const int cnt  = cntS;
  const int nsub = (cnt + 15) >> 4;

  const int lane = tid & 63;
  const int wave = tid >> 6;      // 0..7
  const int hw   = wave >> 1;     // head in group
  const int half = wave & 1;
  const int head = hg * 4 + hw;
  const int quad = lane >> 4;
  const int ec   = lane & 15;

  const int i_q = base_i + ec;
  const int tq  = min(i_q + 1, 2047);
  const unsigned short* qrow = qkv + (size_t)tq * QKVP + head * 64 + quad * 8;
  const bf16x8 qb0 = *(const bf16x8*)(qrow);
  const bf16x8 qb1 = *(const bf16x8*)(qrow + 32);

  f32x4 Od[4] = {{0,0,0,0},{0,0,0,0},{0,0,0,0},{0,0,0,0}};
  float m = -1e30f, l = 0.0f;

  for (int sub = half; sub < nsub; sub += 2) {
    const int base = sub * 16;
    const int tok_e = list[base + ec];
    const int4 tokv = *(const int4*)&list[base + quad * 4];
    const int tk[4] = {tokv.x, tokv.y, tokv.z, tokv.w};

    f32x4 S = {0, 0, 0, 0};
    {
      const int t0 = (tok_e > 2047) ? 0 : tok_e;
      const unsigned short* kr = qkv + (size_t)t0 * QKVP + 512 + head * 64 + quad * 8;
      const bf16x8 kf0 = *(const bf16x8*)(kr);
      const bf16x8 kf1 = *(const bf16x8*)(kr + 32);
      S = __builtin_amdgcn_mfma_f32_16x16x32_bf16(kf0, qb0, S, 0, 0, 0);
      S = __builtin_amdgcn_mfma_f32_16x16x32_bf16(kf1, qb1, S, 0, 0, 0);
    }

    float Sm[4];
#pragma unroll
    for (int r = 0; r < 4; ++r) {
      const int tok = tk[r];
      const int idx = tok - 1;
      const bool v = (tok == 0) ||
                     ((idx <= i_q) && ((unsigned)((idx & 31) - (w0 + ec) + 2) <= 4u));
      Sm[r] = v ? S[r] * 0.125f : -1e30f;
    }
    float mx = fmaxf(fmaxf(Sm[0], Sm[1]), fmaxf(Sm[2], Sm[3]));
    mx = fmaxf(mx, __shfl_xor(mx, 16, 64));
    mx = fmaxf(mx, __shfl_xor(mx, 32, 64));
    const float mn = fmaxf(m, mx);
    const float corr = __expf(m - mn);
    m = mn;
    const float p0 = __expf(Sm[0] - mn);
    const float p1 = __expf(Sm[1] - mn);
    const float p2 = __expf(Sm[2] - mn);
    const float p3 = __expf(Sm[3] - mn);
    float rs = (p0 + p1) + (p2 + p3);
    rs += __shfl_xor(rs, 16, 64);
    rs += __shfl_xor(rs, 32, 64);
    l = l * corr + rs;

    bf16x8 pf;
    pf[0] = (short)f2b(p0); pf[1] = (short)f2b(p1);
    pf[2] = (short)f2b(p2); pf[3] = (short)f2b(p3);
    pf[4] = 0; pf[5] = 0; pf[6] = 0; pf[7] = 0;

    const unsigned short* vp[4];
#pragma unroll
    for (int j = 0; j < 4; ++j) {
      const int tv = (tk[j] > 2047) ? 0 : tk[j];
      vp[j] = qkv + (size_t)tv * QKVP + 1024 + head * 64 + ec;
    }
#pragma unroll
    for (int dt = 0; dt < 4; ++dt) {
      bf16x8 vf;
#pragma unroll
      for (int j = 0; j < 4; ++j) vf[j] = (short)vp[j][dt * 16];
      vf[4] = 0; vf[5] = 0; vf[6] = 0; vf[7] = 0;
#pragma unroll
      for (int r = 0; r < 4; ++r) Od[dt][r] *= corr;
      Od[dt] = __builtin_amdgcn_mfma_f32_16x16x32_bf16(vf, pf, Od[dt], 0, 0, 0);
    }
  }

  // merge halves
  if (half == 1) {
#pragma unroll
    for (int dt = 0; dt < 4; ++dt)
      *(f32x4*)&mOd[hw][ec][dt * 16 + quad * 4] = Od[dt];
    if (quad == 0) { mM[hw][ec] = m; mL[hw][ec] = l; }
  }
  __syncthreads();
  if (half == 0 && i_q <= 2046) {
    const float m1 = mM[hw][ec], l1 = mL[hw][ec];
    const float mm = fmaxf(m, m1);
    const float c0 = __expf(m - mm), c1 = __expf(m1 - mm);
    const float rl = 1.0f / (l * c0 + l1 * c1);
    unsigned short* ob = O + (size_t)(i_q + 1) * 512 + head * 64 + quad * 4;
#pragma unroll
    for (int dt = 0; dt < 4; ++dt) {
      const f32x4 o1 = *(const f32x4*)&mOd[hw][ec][dt * 16 + quad * 4];
      ushort4 u;
      u.x = f2b((Od[dt][0] * c0 + o1[0] * c1) * rl);
      u.y = f2b((Od[dt][1] * c0 + o1[1] * c1) * rl);
      u.z = f2b((Od[dt][2] * c0 + o1[2] * c1) * rl);
      u.w = f2b((Od[dt][3] * c0 + o1[3] * c1) * rl);
      *(ushort4*)(ob + dt * 16) = u;
    }
  }
}

// ---------------- launch ----------------

extern "C" void kernel_launch(void* const* d_in, const int* in_sizes, int n_in,
                              void* d_out, int out_size, void* d_ws, size_t ws_size,
                              hipStream_t stream) {
  const float* x     = (const float*)d_in[0];
  const float* w_qkv = (const float*)d_in[1];
  const float* w_out = (const float*)d_in[2];
  const float* b_out = (const float*)d_in[3];
  float* out = (float*)d_out;

  char* ws = (char*)d_ws;
  unsigned short* qkvb  = (unsigned short*)(ws);             // 2048x1536 bf16
  unsigned short* wqkvT = (unsigned short*)(ws + 6291456);   // 1536x512
  unsigned short* woutT = (unsigned short*)(ws + 7864320);   // 512x512
  unsigned short* Ob    = (unsigned short*)(ws + 8388608);   // 2048x512

  hipLaunchKernelGGL(prep_w, dim3(1024), dim3(256), 0, stream, w_qkv, w_out, wqkvT, woutT);

  hipLaunchKernelGGL(gemm_qkv, dim3(12, 32), dim3(256), 0, stream, x, wqkvT, qkvb);

  hipLaunchKernelGGL(attn_mfma, dim3(129, 2), dim3(512), 0, stream, qkvb, Ob);

  hipLaunchKernelGGL(gemm_out, dim3(8, 32), dim3(256), 0, stream, Ob, woutT, b_out, out);
}